// Round 1
// baseline (283.370 us; speedup 1.0000x reference)
//
#include <hip/hip_runtime.h>
#include <hip/hip_bf16.h>
#include <stdint.h>

typedef short bf16x8 __attribute__((ext_vector_type(8)));
typedef float f32x4 __attribute__((ext_vector_type(4)));
typedef unsigned short u16;

__device__ __forceinline__ u16 f2bf(float f) {
  uint32_t u = __builtin_bit_cast(uint32_t, f);
  u = (u + 0x7FFFu + ((u >> 16) & 1u)) >> 16;
  return (u16)u;
}

// ---------------- straight f32 -> bf16 (x) ----------------
__global__ void conv_x(const float* __restrict__ src, u16* __restrict__ dst) {
  int i = blockIdx.x * blockDim.x + threadIdx.x;
  float4 v = ((const float4*)src)[i];
  ushort4 o;
  o.x = f2bf(v.x); o.y = f2bf(v.y); o.z = f2bf(v.z); o.w = f2bf(v.w);
  ((ushort4*)dst)[i] = o;
}

// ------- transpose [R][1024] f32 (rows k, cols h) -> WdT[h][5120] bf16 -------
__global__ void d_transpose(const float* __restrict__ src, u16* __restrict__ dst, int kbase) {
  __shared__ float t[64][65];
  const int tid = threadIdx.x;
  const int k0 = blockIdx.x * 64, h0 = blockIdx.y * 64;
#pragma unroll
  for (int p = 0; p < 4; ++p) {
    int r = p * 16 + (tid >> 4), c = (tid & 15) * 4;
    float4 v = *(const float4*)&src[(size_t)(k0 + r) * 1024 + h0 + c];
    t[r][c] = v.x; t[r][c + 1] = v.y; t[r][c + 2] = v.z; t[r][c + 3] = v.w;
  }
  __syncthreads();
#pragma unroll
  for (int p = 0; p < 4; ++p) {
    int hl = p * 16 + (tid >> 4), kl = (tid & 15) * 4;
    ushort4 o;
    o.x = f2bf(t[kl][hl]); o.y = f2bf(t[kl + 1][hl]);
    o.z = f2bf(t[kl + 2][hl]); o.w = f2bf(t[kl + 3][hl]);
    *(ushort4*)&dst[(size_t)(h0 + hl) * 5120 + kbase + k0 + kl] = o;
  }
}

// ------- transpose+remap gate/up [1024][C] f32 -> WpT[p][1024] bf16 -------
// p = pbase + 64*(d>>5) + (d&31);  pbase carries expert offset and +32 for "up"
__global__ void gu_transpose(const float* __restrict__ src, u16* __restrict__ dst, int pbase, int C) {
  __shared__ float t[64][65];
  const int tid = threadIdx.x;
  const int d0 = blockIdx.x * 64, h0 = blockIdx.y * 64;
#pragma unroll
  for (int p = 0; p < 4; ++p) {
    int hl = p * 16 + (tid >> 4), dl = (tid & 15) * 4;
    float4 v = *(const float4*)&src[(size_t)(h0 + hl) * C + d0 + dl];
    t[hl][dl] = v.x; t[hl][dl + 1] = v.y; t[hl][dl + 2] = v.z; t[hl][dl + 3] = v.w;
  }
  __syncthreads();
#pragma unroll
  for (int p = 0; p < 4; ++p) {
    int dl = p * 16 + (tid >> 4), hl = (tid & 15) * 4;
    int d = d0 + dl;
    int prow = pbase + ((d >> 5) << 6) + (d & 31);
    ushort4 o;
    o.x = f2bf(t[hl][dl]); o.y = f2bf(t[hl + 1][dl]);
    o.z = f2bf(t[hl + 2][dl]); o.w = f2bf(t[hl + 3][dl]);
    *(ushort4*)&dst[(size_t)prow * 1024 + h0 + hl] = o;
  }
}

// ---------------- router: logits -> softmax -> top-2 -> dense coef [T][8] ----------------
__global__ void router_kernel(const float* __restrict__ x, const float* __restrict__ rw,
                              float* __restrict__ coef) {
  const int l = threadIdx.x & 63;
  const int t = blockIdx.x * 4 + (threadIdx.x >> 6);
  const float* xr = x + (size_t)t * 1024;
  float acc[8];
#pragma unroll
  for (int e = 0; e < 8; ++e) acc[e] = 0.f;
  for (int it = 0; it < 16; ++it) {
    int h = it * 64 + l;
    float xv = xr[h];
    float4 r0 = *(const float4*)&rw[h * 8];
    float4 r1 = *(const float4*)&rw[h * 8 + 4];
    acc[0] += xv * r0.x; acc[1] += xv * r0.y; acc[2] += xv * r0.z; acc[3] += xv * r0.w;
    acc[4] += xv * r1.x; acc[5] += xv * r1.y; acc[6] += xv * r1.z; acc[7] += xv * r1.w;
  }
#pragma unroll
  for (int off = 32; off >= 1; off >>= 1) {
#pragma unroll
    for (int e = 0; e < 8; ++e) acc[e] += __shfl_xor(acc[e], off, 64);
  }
  if (l == 0) {
    float m = acc[0];
#pragma unroll
    for (int e = 1; e < 8; ++e) m = fmaxf(m, acc[e]);
    float p[8], s = 0.f;
#pragma unroll
    for (int e = 0; e < 8; ++e) { p[e] = expf(acc[e] - m); s += p[e]; }
    int i1 = 0;
#pragma unroll
    for (int e = 1; e < 8; ++e) if (p[e] > p[i1]) i1 = e;
    int i2 = (i1 == 0) ? 1 : 0;
#pragma unroll
    for (int e = 0; e < 8; ++e) if (e != i1 && p[e] > p[i2]) i2 = e;
    float inv = 1.f / s;
#pragma unroll
    for (int e = 0; e < 8; ++e) coef[t * 8 + e] = (e == i1 || e == i2) ? p[e] * inv : 0.f;
  }
}

// ---------------- fused gate/up GEMM + SwiGLU + coef epilogue ----------------
// C[4096 x 10240] = Xb[4096 x 1024] * WpT^T ; packed cols: per 64-block = 32 gate + 32 up
__global__ __launch_bounds__(256) void gu_gemm(const u16* __restrict__ Xb, const u16* __restrict__ WpT,
                                               const float* __restrict__ coef, u16* __restrict__ H) {
  __shared__ __align__(16) u16 As[2][128 * 32];
  __shared__ __align__(16) u16 Bs[2][128 * 32];
  const int tid = threadIdx.x;
  const int l = tid & 63, l15 = l & 15, lg = l >> 4;
  const int w = tid >> 6, wr = w >> 1, wc = w & 1;
  const int m0 = blockIdx.y * 128, n0 = blockIdx.x * 128;
  const int ar = tid >> 2, ac = (tid & 3) * 8;

  const u16* Ag = Xb + (size_t)(m0 + ar) * 1024 + ac;
  const u16* Bg = WpT + (size_t)(n0 + ar) * 1024 + ac;

  f32x4 acc[4][4];
#pragma unroll
  for (int m = 0; m < 4; ++m)
#pragma unroll
    for (int n = 0; n < 4; ++n) acc[m][n] = {0.f, 0.f, 0.f, 0.f};

  uint4 ra0 = *(const uint4*)Ag;
  uint4 ra1 = *(const uint4*)(Ag + 64 * 1024);
  uint4 rb0 = *(const uint4*)Bg;
  uint4 rb1 = *(const uint4*)(Bg + 64 * 1024);
  *(uint4*)&As[0][ar * 32 + ac] = ra0;
  *(uint4*)&As[0][(ar + 64) * 32 + ac] = ra1;
  *(uint4*)&Bs[0][ar * 32 + ac] = rb0;
  *(uint4*)&Bs[0][(ar + 64) * 32 + ac] = rb1;
  __syncthreads();

  int cur = 0;
  for (int kt = 0; kt < 32; ++kt) {
    if (kt < 31) {
      const u16* a = Ag + (kt + 1) * 32;
      const u16* b = Bg + (kt + 1) * 32;
      ra0 = *(const uint4*)a; ra1 = *(const uint4*)(a + 64 * 1024);
      rb0 = *(const uint4*)b; rb1 = *(const uint4*)(b + 64 * 1024);
    }
    bf16x8 af[4], bfr[4];
#pragma unroll
    for (int m = 0; m < 4; ++m)
      af[m] = *(const bf16x8*)&As[cur][(wr * 64 + m * 16 + l15) * 32 + lg * 8];
#pragma unroll
    for (int n = 0; n < 4; ++n)
      bfr[n] = *(const bf16x8*)&Bs[cur][(wc * 64 + n * 16 + l15) * 32 + lg * 8];
#pragma unroll
    for (int m = 0; m < 4; ++m)
#pragma unroll
      for (int n = 0; n < 4; ++n)
        acc[m][n] = __builtin_amdgcn_mfma_f32_16x16x32_bf16(af[m], bfr[n], acc[m][n], 0, 0, 0);
    if (kt < 31) {
      int nb = cur ^ 1;
      *(uint4*)&As[nb][ar * 32 + ac] = ra0;
      *(uint4*)&As[nb][(ar + 64) * 32 + ac] = ra1;
      *(uint4*)&Bs[nb][ar * 32 + ac] = rb0;
      *(uint4*)&Bs[nb][(ar + 64) * 32 + ac] = rb1;
    }
    __syncthreads();
    cur ^= 1;
  }

  // epilogue: H[t, c] = silu(gate)*up*scale ; wave owns packed cols [n0+wc*64, +64) => 32 hidden cols
  const int hb = (n0 + wc * 64) >> 1;
  const int rbase = m0 + wr * 64 + lg * 4;
#pragma unroll
  for (int m = 0; m < 4; ++m) {
#pragma unroll
    for (int nt = 0; nt < 2; ++nt) {
      int colh = hb + nt * 16 + l15;
#pragma unroll
      for (int j = 0; j < 4; ++j) {
        int row = rbase + m * 16 + j;
        float g = acc[m][nt][j];
        float u = acc[m][nt + 2][j];
        float sc = (colh < 4096) ? coef[row * 8 + (colh >> 9)] : 1.f;
        float hv = g / (1.f + __expf(-g)) * u * sc;
        H[(size_t)row * 5120 + colh] = f2bf(hv);
      }
    }
  }
}

// ---------------- combined down GEMM: out = H[4096x5120] * Wd_all[5120x1024] ----------------
__global__ __launch_bounds__(256) void down_gemm(const u16* __restrict__ Hm, const u16* __restrict__ WdT,
                                                 float* __restrict__ out) {
  __shared__ __align__(16) u16 As[2][128 * 32];
  __shared__ __align__(16) u16 Bs[2][64 * 32];
  const int tid = threadIdx.x;
  const int l = tid & 63, l15 = l & 15, lg = l >> 4;
  const int w = tid >> 6, wr = w >> 1, wc = w & 1;
  const int m0 = blockIdx.y * 128, n0 = blockIdx.x * 64;
  const int ar = tid >> 2, ac = (tid & 3) * 8;

  const u16* Ag = Hm + (size_t)(m0 + ar) * 5120 + ac;
  const u16* Bg = WdT + (size_t)(n0 + ar) * 5120 + ac;

  f32x4 acc[4][2];
#pragma unroll
  for (int m = 0; m < 4; ++m)
#pragma unroll
    for (int n = 0; n < 2; ++n) acc[m][n] = {0.f, 0.f, 0.f, 0.f};

  uint4 ra0 = *(const uint4*)Ag;
  uint4 ra1 = *(const uint4*)(Ag + 64 * 5120);
  uint4 rb0 = *(const uint4*)Bg;
  *(uint4*)&As[0][ar * 32 + ac] = ra0;
  *(uint4*)&As[0][(ar + 64) * 32 + ac] = ra1;
  *(uint4*)&Bs[0][ar * 32 + ac] = rb0;
  __syncthreads();

  int cur = 0;
  for (int kt = 0; kt < 160; ++kt) {
    if (kt < 159) {
      const u16* a = Ag + (kt + 1) * 32;
      const u16* b = Bg + (kt + 1) * 32;
      ra0 = *(const uint4*)a; ra1 = *(const uint4*)(a + 64 * 5120);
      rb0 = *(const uint4*)b;
    }
    bf16x8 af[4], bfr[2];
#pragma unroll
    for (int m = 0; m < 4; ++m)
      af[m] = *(const bf16x8*)&As[cur][(wr * 64 + m * 16 + l15) * 32 + lg * 8];
#pragma unroll
    for (int n = 0; n < 2; ++n)
      bfr[n] = *(const bf16x8*)&Bs[cur][(wc * 32 + n * 16 + l15) * 32 + lg * 8];
#pragma unroll
    for (int m = 0; m < 4; ++m)
#pragma unroll
      for (int n = 0; n < 2; ++n)
        acc[m][n] = __builtin_amdgcn_mfma_f32_16x16x32_bf16(af[m], bfr[n], acc[m][n], 0, 0, 0);
    if (kt < 159) {
      int nb = cur ^ 1;
      *(uint4*)&As[nb][ar * 32 + ac] = ra0;
      *(uint4*)&As[nb][(ar + 64) * 32 + ac] = ra1;
      *(uint4*)&Bs[nb][ar * 32 + ac] = rb0;
    }
    __syncthreads();
    cur ^= 1;
  }

  const int rbase = m0 + wr * 64 + lg * 4;
  const int cb = n0 + wc * 32;
#pragma unroll
  for (int m = 0; m < 4; ++m)
#pragma unroll
    for (int n = 0; n < 2; ++n)
#pragma unroll
      for (int j = 0; j < 4; ++j)
        out[(size_t)(rbase + m * 16 + j) * 1024 + cb + n * 16 + l15] = acc[m][n][j];
}

extern "C" void kernel_launch(void* const* d_in, const int* in_sizes, int n_in,
                              void* d_out, int out_size, void* d_ws, size_t ws_size,
                              hipStream_t stream) {
  const float* x  = (const float*)d_in[0];
  const float* rw = (const float*)d_in[1];
  const float* eg = (const float*)d_in[2];
  const float* eu = (const float*)d_in[3];
  const float* ed = (const float*)d_in[4];
  const float* sg = (const float*)d_in[5];
  const float* su = (const float*)d_in[6];
  const float* sd = (const float*)d_in[7];
  float* out = (float*)d_out;

  char* ws = (char*)d_ws;
  u16*   Xb   = (u16*)(ws);                    // 4096*1024*2      = 8,388,608
  u16*   WpT  = (u16*)(ws + 8388608);          // 10240*1024*2     = 20,971,520
  u16*   WdT  = (u16*)(ws + 29360128);         // 1024*5120*2      = 10,485,760
  u16*   Hm   = (u16*)(ws + 39845888);         // 4096*5120*2      = 41,943,040
  float* coef = (float*)(ws + 81788928);       // 4096*8*4         = 131,072

  // pack / convert
  conv_x<<<4096, 256, 0, stream>>>(x, Xb);
  d_transpose<<<dim3(64, 16), 256, 0, stream>>>(ed, WdT, 0);
  d_transpose<<<dim3(16, 16), 256, 0, stream>>>(sd, WdT, 4096);
  for (int e = 0; e < 8; ++e) {
    gu_transpose<<<dim3(8, 16), 256, 0, stream>>>(eg + (size_t)e * 524288, WpT, e * 1024, 512);
    gu_transpose<<<dim3(8, 16), 256, 0, stream>>>(eu + (size_t)e * 524288, WpT, e * 1024 + 32, 512);
  }
  gu_transpose<<<dim3(16, 16), 256, 0, stream>>>(sg, WpT, 8192, 1024);
  gu_transpose<<<dim3(16, 16), 256, 0, stream>>>(su, WpT, 8192 + 32, 1024);

  // router coefficients
  router_kernel<<<1024, 256, 0, stream>>>(x, rw, coef);

  // fused gate/up + SwiGLU + routing scale
  gu_gemm<<<dim3(80, 32), 256, 0, stream>>>(Xb, WpT, coef, Hm);

  // combined expert-down + shared-down projection
  down_gemm<<<dim3(16, 32), 256, 0, stream>>>(Hm, WdT, out);
}

// Round 2
// 278.645 us; speedup vs baseline: 1.0170x; 1.0170x over previous
//
#include <hip/hip_runtime.h>
#include <hip/hip_bf16.h>
#include <stdint.h>

typedef short bf16x8 __attribute__((ext_vector_type(8)));
typedef float f32x4 __attribute__((ext_vector_type(4)));
typedef unsigned short u16;

#define GLOAD16(gp, lp)                                                        \
  __builtin_amdgcn_global_load_lds(                                            \
      (const __attribute__((address_space(1))) void*)(gp),                     \
      (__attribute__((address_space(3))) void*)(lp), 16, 0, 0)

__device__ __forceinline__ u16 f2bf(float f) {
  uint32_t u = __builtin_bit_cast(uint32_t, f);
  u = (u + 0x7FFFu + ((u >> 16) & 1u)) >> 16;
  return (u16)u;
}

// ---------------- straight f32 -> bf16 (x) ----------------
__global__ void conv_x(const float* __restrict__ src, u16* __restrict__ dst) {
  int i = blockIdx.x * blockDim.x + threadIdx.x;
  float4 v = ((const float4*)src)[i];
  ushort4 o;
  o.x = f2bf(v.x); o.y = f2bf(v.y); o.z = f2bf(v.z); o.w = f2bf(v.w);
  ((ushort4*)dst)[i] = o;
}

// ---------------- all weight transposes, one launch ----------------
// blocks 0..1279    : down-type  [R][1024] -> WdT[h][5120]
//   0..1023  ed (R=4096, kbase=0), 1024..1279 sd (R=1024, kbase=4096)
// blocks 1280..3839 : gate/up-type [1024][C] -> WpT[p][1024]
//   1280..3327 experts (16 slices of 128: e*2+up), 3328..3839 shared (sg,su)
__global__ void pack_w(const float* __restrict__ ed, const float* __restrict__ sd,
                       const float* __restrict__ eg, const float* __restrict__ eu,
                       const float* __restrict__ sg, const float* __restrict__ su,
                       u16* __restrict__ WdT, u16* __restrict__ WpT) {
  __shared__ float t[64][65];
  const int tid = threadIdx.x;
  const int b = blockIdx.x;
  if (b < 1280) {
    const float* src; int kbase, kt, ht;
    if (b < 1024) { src = ed; kbase = 0;    kt = b >> 4;          ht = b & 15; }
    else          { src = sd; kbase = 4096; kt = (b - 1024) >> 4; ht = b & 15; }
    const int k0 = kt * 64, h0 = ht * 64;
#pragma unroll
    for (int p = 0; p < 4; ++p) {
      int r = p * 16 + (tid >> 4), c = (tid & 15) * 4;
      float4 v = *(const float4*)&src[(size_t)(k0 + r) * 1024 + h0 + c];
      t[r][c] = v.x; t[r][c + 1] = v.y; t[r][c + 2] = v.z; t[r][c + 3] = v.w;
    }
    __syncthreads();
#pragma unroll
    for (int p = 0; p < 4; ++p) {
      int hl = p * 16 + (tid >> 4), kl = (tid & 15) * 4;
      ushort4 o;
      o.x = f2bf(t[kl][hl]);     o.y = f2bf(t[kl + 1][hl]);
      o.z = f2bf(t[kl + 2][hl]); o.w = f2bf(t[kl + 3][hl]);
      *(ushort4*)&WdT[(size_t)(h0 + hl) * 5120 + kbase + k0 + kl] = o;
    }
  } else {
    int bb = b - 1280;
    const float* src; int pbase, C, dt, ht;
    if (bb < 2048) {
      int slice = bb >> 7, r = bb & 127;
      int e = slice >> 1; int up = slice & 1;
      src = (up ? eu : eg) + (size_t)e * 524288;
      pbase = e * 1024 + up * 32; C = 512;
      dt = r >> 4; ht = r & 15;
    } else {
      int r = bb - 2048;
      int up = r >= 256; r &= 255;
      src = up ? su : sg; pbase = 8192 + up * 32; C = 1024;
      dt = r >> 4; ht = r & 15;
    }
    const int d0 = dt * 64, h0 = ht * 64;
#pragma unroll
    for (int p = 0; p < 4; ++p) {
      int hl = p * 16 + (tid >> 4), dl = (tid & 15) * 4;
      float4 v = *(const float4*)&src[(size_t)(h0 + hl) * C + d0 + dl];
      t[hl][dl] = v.x; t[hl][dl + 1] = v.y; t[hl][dl + 2] = v.z; t[hl][dl + 3] = v.w;
    }
    __syncthreads();
#pragma unroll
    for (int p = 0; p < 4; ++p) {
      int dl = p * 16 + (tid >> 4), hl = (tid & 15) * 4;
      int d = d0 + dl;
      int prow = pbase + ((d >> 5) << 6) + (d & 31);
      ushort4 o;
      o.x = f2bf(t[hl][dl]);     o.y = f2bf(t[hl + 1][dl]);
      o.z = f2bf(t[hl + 2][dl]); o.w = f2bf(t[hl + 3][dl]);
      *(ushort4*)&WpT[(size_t)prow * 1024 + h0 + hl] = o;
    }
  }
}

// ---------------- router: logits -> softmax -> top-2 -> dense coef [T][8] ----------------
__global__ void router_kernel(const float* __restrict__ x, const float* __restrict__ rw,
                              float* __restrict__ coef) {
  const int l = threadIdx.x & 63;
  const int t = blockIdx.x * 4 + (threadIdx.x >> 6);
  const float* xr = x + (size_t)t * 1024;
  float acc[8];
#pragma unroll
  for (int e = 0; e < 8; ++e) acc[e] = 0.f;
  for (int it = 0; it < 16; ++it) {
    int h = it * 64 + l;
    float xv = xr[h];
    float4 r0 = *(const float4*)&rw[h * 8];
    float4 r1 = *(const float4*)&rw[h * 8 + 4];
    acc[0] += xv * r0.x; acc[1] += xv * r0.y; acc[2] += xv * r0.z; acc[3] += xv * r0.w;
    acc[4] += xv * r1.x; acc[5] += xv * r1.y; acc[6] += xv * r1.z; acc[7] += xv * r1.w;
  }
#pragma unroll
  for (int off = 32; off >= 1; off >>= 1) {
#pragma unroll
    for (int e = 0; e < 8; ++e) acc[e] += __shfl_xor(acc[e], off, 64);
  }
  if (l == 0) {
    float m = acc[0];
#pragma unroll
    for (int e = 1; e < 8; ++e) m = fmaxf(m, acc[e]);
    float p[8], s = 0.f;
#pragma unroll
    for (int e = 0; e < 8; ++e) { p[e] = expf(acc[e] - m); s += p[e]; }
    int i1 = 0;
#pragma unroll
    for (int e = 1; e < 8; ++e) if (p[e] > p[i1]) i1 = e;
    int i2 = (i1 == 0) ? 1 : 0;
#pragma unroll
    for (int e = 0; e < 8; ++e) if (e != i1 && p[e] > p[i2]) i2 = e;
    float inv = 1.f / s;
#pragma unroll
    for (int e = 0; e < 8; ++e) coef[t * 8 + e] = (e == i1 || e == i2) ? p[e] * inv : 0.f;
  }
}

// stage a 128x32 bf16 tile (row stride LDA u16) into linear LDS [128][32]
template <int LDA>
__device__ __forceinline__ void stage_tile(const u16* gbase, u16* lbase, int lane, int wv) {
#pragma unroll
  for (int c = 0; c < 2; ++c) {
    int chunk = wv * 2 + c;
    int row = chunk * 16 + (lane >> 2);
    const u16* g = gbase + (size_t)row * LDA + (lane & 3) * 8;
    GLOAD16(g, lbase + chunk * 512);
  }
}

// ---------------- fused gate/up GEMM + SwiGLU + coef epilogue ----------------
__global__ __launch_bounds__(256) void gu_gemm(const u16* __restrict__ Xb, const u16* __restrict__ WpT,
                                               const float* __restrict__ coef, u16* __restrict__ H) {
  __shared__ __align__(16) u16 As[2][128 * 32];
  __shared__ __align__(16) u16 Bs[2][128 * 32];
  const int tid = threadIdx.x;
  const int l = tid & 63, l15 = l & 15, lg = l >> 4;
  const int wv = tid >> 6, wr = wv >> 1, wc = wv & 1;
  const int m0 = blockIdx.y * 128, n0 = blockIdx.x * 128;

  const u16* Ag = Xb + (size_t)m0 * 1024;
  const u16* Bg = WpT + (size_t)n0 * 1024;

  f32x4 acc[4][4];
#pragma unroll
  for (int m = 0; m < 4; ++m)
#pragma unroll
    for (int n = 0; n < 4; ++n) acc[m][n] = {0.f, 0.f, 0.f, 0.f};

  stage_tile<1024>(Ag, &As[0][0], l, wv);
  stage_tile<1024>(Bg, &Bs[0][0], l, wv);
  __syncthreads();

  int cur = 0;
  for (int kt = 0; kt < 32; ++kt) {
    if (kt < 31) {
      stage_tile<1024>(Ag + (kt + 1) * 32, &As[cur ^ 1][0], l, wv);
      stage_tile<1024>(Bg + (kt + 1) * 32, &Bs[cur ^ 1][0], l, wv);
    }
    bf16x8 af[4], bfr[4];
#pragma unroll
    for (int m = 0; m < 4; ++m)
      af[m] = *(const bf16x8*)&As[cur][(wr * 64 + m * 16 + l15) * 32 + lg * 8];
#pragma unroll
    for (int n = 0; n < 4; ++n)
      bfr[n] = *(const bf16x8*)&Bs[cur][(wc * 64 + n * 16 + l15) * 32 + lg * 8];
#pragma unroll
    for (int m = 0; m < 4; ++m)
#pragma unroll
      for (int n = 0; n < 4; ++n)
        acc[m][n] = __builtin_amdgcn_mfma_f32_16x16x32_bf16(af[m], bfr[n], acc[m][n], 0, 0, 0);
    __syncthreads();
    cur ^= 1;
  }

  // epilogue: H[t, c] = silu(gate)*up*scale ; packed col block = 32 gate + 32 up
  const int hb = (n0 + wc * 64) >> 1;
  const int rbase = m0 + wr * 64 + lg * 4;
#pragma unroll
  for (int m = 0; m < 4; ++m) {
#pragma unroll
    for (int nt = 0; nt < 2; ++nt) {
      int colh = hb + nt * 16 + l15;
#pragma unroll
      for (int j = 0; j < 4; ++j) {
        int row = rbase + m * 16 + j;
        float g = acc[m][nt][j];
        float u = acc[m][nt + 2][j];
        float sc = (colh < 4096) ? coef[row * 8 + (colh >> 9)] : 1.f;
        float hv = g / (1.f + __expf(-g)) * u * sc;
        H[(size_t)row * 5120 + colh] = f2bf(hv);
      }
    }
  }
}

// ---------------- combined down GEMM: out = H[4096x5120] * Wd_all[5120x1024] ----------------
__global__ __launch_bounds__(256) void down_gemm(const u16* __restrict__ Hm, const u16* __restrict__ WdT,
                                                 float* __restrict__ out) {
  __shared__ __align__(16) u16 As[2][128 * 32];
  __shared__ __align__(16) u16 Bs[2][128 * 32];
  const int tid = threadIdx.x;
  const int l = tid & 63, l15 = l & 15, lg = l >> 4;
  const int wv = tid >> 6, wr = wv >> 1, wc = wv & 1;
  const int m0 = blockIdx.y * 128, n0 = blockIdx.x * 128;

  const u16* Ag = Hm + (size_t)m0 * 5120;
  const u16* Bg = WdT + (size_t)n0 * 5120;

  f32x4 acc[4][4];
#pragma unroll
  for (int m = 0; m < 4; ++m)
#pragma unroll
    for (int n = 0; n < 4; ++n) acc[m][n] = {0.f, 0.f, 0.f, 0.f};

  stage_tile<5120>(Ag, &As[0][0], l, wv);
  stage_tile<5120>(Bg, &Bs[0][0], l, wv);
  __syncthreads();

  int cur = 0;
  for (int kt = 0; kt < 160; ++kt) {
    if (kt < 159) {
      stage_tile<5120>(Ag + (kt + 1) * 32, &As[cur ^ 1][0], l, wv);
      stage_tile<5120>(Bg + (kt + 1) * 32, &Bs[cur ^ 1][0], l, wv);
    }
    bf16x8 af[4], bfr[4];
#pragma unroll
    for (int m = 0; m < 4; ++m)
      af[m] = *(const bf16x8*)&As[cur][(wr * 64 + m * 16 + l15) * 32 + lg * 8];
#pragma unroll
    for (int n = 0; n < 4; ++n)
      bfr[n] = *(const bf16x8*)&Bs[cur][(wc * 64 + n * 16 + l15) * 32 + lg * 8];
#pragma unroll
    for (int m = 0; m < 4; ++m)
#pragma unroll
      for (int n = 0; n < 4; ++n)
        acc[m][n] = __builtin_amdgcn_mfma_f32_16x16x32_bf16(af[m], bfr[n], acc[m][n], 0, 0, 0);
    __syncthreads();
    cur ^= 1;
  }

  const int rbase = m0 + wr * 64 + lg * 4;
  const int cb = n0 + wc * 64;
#pragma unroll
  for (int m = 0; m < 4; ++m)
#pragma unroll
    for (int n = 0; n < 4; ++n)
#pragma unroll
      for (int j = 0; j < 4; ++j)
        out[(size_t)(rbase + m * 16 + j) * 1024 + cb + n * 16 + l15] = acc[m][n][j];
}

extern "C" void kernel_launch(void* const* d_in, const int* in_sizes, int n_in,
                              void* d_out, int out_size, void* d_ws, size_t ws_size,
                              hipStream_t stream) {
  const float* x  = (const float*)d_in[0];
  const float* rw = (const float*)d_in[1];
  const float* eg = (const float*)d_in[2];
  const float* eu = (const float*)d_in[3];
  const float* ed = (const float*)d_in[4];
  const float* sg = (const float*)d_in[5];
  const float* su = (const float*)d_in[6];
  const float* sd = (const float*)d_in[7];
  float* out = (float*)d_out;

  char* ws = (char*)d_ws;
  u16*   Xb   = (u16*)(ws);                    // 4096*1024*2      = 8,388,608
  u16*   WpT  = (u16*)(ws + 8388608);          // 10240*1024*2     = 20,971,520
  u16*   WdT  = (u16*)(ws + 29360128);         // 1024*5120*2      = 10,485,760
  u16*   Hm   = (u16*)(ws + 39845888);         // 4096*5120*2      = 41,943,040
  float* coef = (float*)(ws + 81788928);       // 4096*8*4         = 131,072

  conv_x<<<4096, 256, 0, stream>>>(x, Xb);
  pack_w<<<3840, 256, 0, stream>>>(ed, sd, eg, eu, sg, su, WdT, WpT);
  router_kernel<<<1024, 256, 0, stream>>>(x, rw, coef);

  gu_gemm<<<dim3(80, 32), 256, 0, stream>>>(Xb, WpT, coef, Hm);
  down_gemm<<<dim3(8, 32), 256, 0, stream>>>(Hm, WdT, out);
}

// Round 3
// 206.328 us; speedup vs baseline: 1.3734x; 1.3505x over previous
//
#include <hip/hip_runtime.h>
#include <hip/hip_bf16.h>
#include <stdint.h>

typedef short bf16x8 __attribute__((ext_vector_type(8)));
typedef float f32x4 __attribute__((ext_vector_type(4)));
typedef unsigned short u16;

#define GLOAD16(gp, lp)                                                        \
  __builtin_amdgcn_global_load_lds(                                            \
      (const __attribute__((address_space(1))) void*)(gp),                     \
      (__attribute__((address_space(3))) void*)(lp), 16, 0, 0)

__device__ __forceinline__ u16 f2bf(float f) {
  uint32_t u = __builtin_bit_cast(uint32_t, f);
  u = (u + 0x7FFFu + ((u >> 16) & 1u)) >> 16;
  return (u16)u;
}

// physical byte offset within an LDS region for logical (row, 16B-unit u∈0..3)
// row-pair line layout: pairs of rows share a 128B line; 3-bit slot XOR-swizzled
// by line index -> frag reads (16 rows, fixed u) hit each 16B slot exactly 2x (free).
__device__ __forceinline__ int swzoff(int row, int u) {
  int p = row >> 1;
  int us = ((row & 1) * 4 + u) ^ (p & 7);
  return p * 128 + us * 16;
}

// ================= mega pre-pass: all packing + router in ONE launch ========
// b in [0,1280)    : down-type transpose [R][1024] f32 -> WdT[h][5120] bf16
// b in [1280,3840) : gate/up transpose+remap -> WpT[p][1024] bf16
// b in [3840,4864) : router (4 tokens/block)
// b in [4864,6912) : x f32 -> bf16
__global__ void mega(const float* __restrict__ x, const float* __restrict__ rw,
                     const float* __restrict__ eg, const float* __restrict__ eu,
                     const float* __restrict__ ed, const float* __restrict__ sg,
                     const float* __restrict__ su, const float* __restrict__ sd,
                     u16* __restrict__ Xb, u16* __restrict__ WpT,
                     u16* __restrict__ WdT, float* __restrict__ coef) {
  __shared__ float t[64][65];
  const int tid = threadIdx.x;
  const int b = blockIdx.x;
  if (b < 1280) {
    const float* src; int kbase, kt, ht;
    if (b < 1024) { src = ed; kbase = 0;    kt = b >> 4;          ht = b & 15; }
    else          { src = sd; kbase = 4096; kt = (b - 1024) >> 4; ht = b & 15; }
    const int k0 = kt * 64, h0 = ht * 64;
#pragma unroll
    for (int p = 0; p < 4; ++p) {
      int r = p * 16 + (tid >> 4), c = (tid & 15) * 4;
      float4 v = *(const float4*)&src[(size_t)(k0 + r) * 1024 + h0 + c];
      t[r][c] = v.x; t[r][c + 1] = v.y; t[r][c + 2] = v.z; t[r][c + 3] = v.w;
    }
    __syncthreads();
#pragma unroll
    for (int p = 0; p < 4; ++p) {
      int hl = p * 16 + (tid >> 4), kl = (tid & 15) * 4;
      ushort4 o;
      o.x = f2bf(t[kl][hl]);     o.y = f2bf(t[kl + 1][hl]);
      o.z = f2bf(t[kl + 2][hl]); o.w = f2bf(t[kl + 3][hl]);
      *(ushort4*)&WdT[(size_t)(h0 + hl) * 5120 + kbase + k0 + kl] = o;
    }
  } else if (b < 3840) {
    int bb = b - 1280;
    const float* src; int pbase, C, dt, ht;
    if (bb < 2048) {
      int slice = bb >> 7, r = bb & 127;
      int e = slice >> 1; int up = slice & 1;
      src = (up ? eu : eg) + (size_t)e * 524288;
      pbase = e * 1024 + up * 32; C = 512;
      dt = r >> 4; ht = r & 15;
    } else {
      int r = bb - 2048;
      int up = r >= 256; r &= 255;
      src = up ? su : sg; pbase = 8192 + up * 32; C = 1024;
      dt = r >> 4; ht = r & 15;
    }
    const int d0 = dt * 64, h0 = ht * 64;
#pragma unroll
    for (int p = 0; p < 4; ++p) {
      int hl = p * 16 + (tid >> 4), dl = (tid & 15) * 4;
      float4 v = *(const float4*)&src[(size_t)(h0 + hl) * C + d0 + dl];
      t[hl][dl] = v.x; t[hl][dl + 1] = v.y; t[hl][dl + 2] = v.z; t[hl][dl + 3] = v.w;
    }
    __syncthreads();
#pragma unroll
    for (int p = 0; p < 4; ++p) {
      int dl = p * 16 + (tid >> 4), hl = (tid & 15) * 4;
      int d = d0 + dl;
      int prow = pbase + ((d >> 5) << 6) + (d & 31);
      ushort4 o;
      o.x = f2bf(t[hl][dl]);     o.y = f2bf(t[hl + 1][dl]);
      o.z = f2bf(t[hl + 2][dl]); o.w = f2bf(t[hl + 3][dl]);
      *(ushort4*)&WpT[(size_t)prow * 1024 + h0 + hl] = o;
    }
  } else if (b < 4864) {
    const int l = tid & 63;
    const int tok = (b - 3840) * 4 + (tid >> 6);
    const float* xr = x + (size_t)tok * 1024;
    float acc[8];
#pragma unroll
    for (int e = 0; e < 8; ++e) acc[e] = 0.f;
    for (int it = 0; it < 16; ++it) {
      int h = it * 64 + l;
      float xv = xr[h];
      float4 r0 = *(const float4*)&rw[h * 8];
      float4 r1 = *(const float4*)&rw[h * 8 + 4];
      acc[0] += xv * r0.x; acc[1] += xv * r0.y; acc[2] += xv * r0.z; acc[3] += xv * r0.w;
      acc[4] += xv * r1.x; acc[5] += xv * r1.y; acc[6] += xv * r1.z; acc[7] += xv * r1.w;
    }
#pragma unroll
    for (int off = 32; off >= 1; off >>= 1) {
#pragma unroll
      for (int e = 0; e < 8; ++e) acc[e] += __shfl_xor(acc[e], off, 64);
    }
    if (l == 0) {
      float m = acc[0];
#pragma unroll
      for (int e = 1; e < 8; ++e) m = fmaxf(m, acc[e]);
      float p[8], s = 0.f;
#pragma unroll
      for (int e = 0; e < 8; ++e) { p[e] = expf(acc[e] - m); s += p[e]; }
      int i1 = 0;
#pragma unroll
      for (int e = 1; e < 8; ++e) if (p[e] > p[i1]) i1 = e;
      int i2 = (i1 == 0) ? 1 : 0;
#pragma unroll
      for (int e = 0; e < 8; ++e) if (e != i1 && p[e] > p[i2]) i2 = e;
      float inv = 1.f / s;
#pragma unroll
      for (int e = 0; e < 8; ++e) coef[tok * 8 + e] = (e == i1 || e == i2) ? p[e] * inv : 0.f;
    }
  } else {
    int i = (b - 4864) * 512 + tid;
#pragma unroll
    for (int k = 0; k < 2; ++k) {
      float4 v = ((const float4*)x)[i + k * 256];
      ushort4 o;
      o.x = f2bf(v.x); o.y = f2bf(v.y); o.z = f2bf(v.z); o.w = f2bf(v.w);
      ((ushort4*)Xb)[i + k * 256] = o;
    }
  }
}

// ============ counted-vmcnt pipelined GEMM (BK=32, 4-slot LDS ring) =========
// 512 threads = 8 waves (WM x WN), per-wave 64x64 output, acc[4][4].
// Stage tile t+3 while computing tile t; waits are vmcnt(6) (2 tiles in flight),
// never 0 in the main loop. Raw s_barrier, compiler-managed lgkmcnt.
template <int BM, int BN, int WM, int WN, bool GU>
__global__ __launch_bounds__(512, 2) void gemm8p(
    const u16* __restrict__ Ag, const u16* __restrict__ Bg,
    int lda, int ldb, int nt,
    const float* __restrict__ coef, u16* __restrict__ Hout,
    float* __restrict__ Fout, float* __restrict__ Fout2) {
  constexpr int SA = BM / 128;            // A staging sweeps (512 thr x 16B = 8KB each)
  constexpr int SB = BN / 128;
  constexpr int BOFF = BM * 64;           // B region byte offset inside a slot
  constexpr int SLOT = (BM + BN) * 64;    // bytes per ring slot
  __shared__ __align__(16) char lds[4 * SLOT];

  const int tid = threadIdx.x;
  const int l = tid & 63, l15 = l & 15, lg = l >> 4;
  const int wv = tid >> 6;
  const int wr = wv / WN, wc = wv % WN;

  int mT, nT, split = 0;
  if constexpr (GU) {
    int id = blockIdx.x;                   // 1280 blocks: XCD-chunked swizzle
    int swz = (id & 7) * 160 + (id >> 3);
    nT = swz >> 5; mT = swz & 31;          // column-major: B-panel affinity per XCD
  } else {
    int id = blockIdx.x;                   // 256 blocks: [split][m 16][n 8]
    split = id >> 7; int r = id & 127;
    mT = r >> 3; nT = r & 7;
  }
  const int m0 = mT * BM, n0 = nT * BN;
  const int kbase = GU ? 0 : split * 2560; // elements

  // per-thread staging sources (pre-swizzled global addresses, rule #21)
  const char* gA[SA]; int lA[SA];
  const char* gB[SB]; int lB[SB];
#pragma unroll
  for (int j = 0; j < SA; ++j) {
    int L = (j * 512 + tid) * 16;
    int p = L >> 7, uph = (L >> 4) & 7;
    int usw = uph ^ (p & 7);
    int row = 2 * p + (usw >> 2), ulog = usw & 3;
    gA[j] = (const char*)(Ag + (size_t)(m0 + row) * lda + kbase) + ulog * 16;
    lA[j] = L;
  }
#pragma unroll
  for (int j = 0; j < SB; ++j) {
    int L = (j * 512 + tid) * 16;
    int p = L >> 7, uph = (L >> 4) & 7;
    int usw = uph ^ (p & 7);
    int row = 2 * p + (usw >> 2), ulog = usw & 3;
    gB[j] = (const char*)(Bg + (size_t)(n0 + row) * ldb + kbase) + ulog * 16;
    lB[j] = L;
  }

  // per-thread fragment read offsets (swizzled)
  int offA[4], offB[4];
#pragma unroll
  for (int m = 0; m < 4; ++m) offA[m] = swzoff(wr * 64 + m * 16 + l15, lg);
#pragma unroll
  for (int n = 0; n < 4; ++n) offB[n] = BOFF + swzoff(wc * 64 + n * 16 + l15, lg);

  f32x4 acc[4][4];
#pragma unroll
  for (int m = 0; m < 4; ++m)
#pragma unroll
    for (int n = 0; n < 4; ++n) acc[m][n] = {0.f, 0.f, 0.f, 0.f};

#define STAGE(T)                                                               \
  {                                                                            \
    char* sb_ = lds + (((T) & 3) * SLOT);                                      \
    const int tb_ = (T) * 64;                                                  \
    _Pragma("unroll") for (int j = 0; j < SA; ++j)                             \
        GLOAD16(gA[j] + tb_, sb_ + lA[j]);                                     \
    _Pragma("unroll") for (int j = 0; j < SB; ++j)                             \
        GLOAD16(gB[j] + tb_, sb_ + BOFF + lB[j]);                              \
  }

  STAGE(0); STAGE(1); STAGE(2);
  asm volatile("s_waitcnt vmcnt(6)" ::: "memory");
  __builtin_amdgcn_s_barrier();

  for (int t = 0; t < nt; ++t) {
    asm volatile("" ::: "memory");  // fence: next-iter LDS reads can't hoist above barrier
    char* sb = lds + ((t & 3) * SLOT);
    bf16x8 af[4], bfr[4];
#pragma unroll
    for (int m = 0; m < 4; ++m) af[m] = *(const bf16x8*)(sb + offA[m]);
#pragma unroll
    for (int n = 0; n < 4; ++n) bfr[n] = *(const bf16x8*)(sb + offB[n]);
    if (t + 3 < nt) STAGE(t + 3);
    asm volatile("s_waitcnt vmcnt(6)" ::: "memory");
    __builtin_amdgcn_s_barrier();
    __builtin_amdgcn_s_setprio(1);
#pragma unroll
    for (int m = 0; m < 4; ++m)
#pragma unroll
      for (int n = 0; n < 4; ++n)
        acc[m][n] = __builtin_amdgcn_mfma_f32_16x16x32_bf16(af[m], bfr[n], acc[m][n], 0, 0, 0);
    __builtin_amdgcn_s_setprio(0);
    asm volatile("" ::: "memory");
    __builtin_amdgcn_s_barrier();
  }
#undef STAGE

  if constexpr (GU) {
    // SwiGLU + routing-coef epilogue; packed 64-block = 32 gate rows + 32 up rows
    const int rb = m0 + wr * 64 + lg * 4;
    const int hb = (n0 + wc * 64) >> 1;
#pragma unroll
    for (int m = 0; m < 4; ++m)
#pragma unroll
      for (int q = 0; q < 2; ++q) {
        int colh = hb + q * 16 + l15;
#pragma unroll
        for (int j = 0; j < 4; ++j) {
          int row = rb + m * 16 + j;
          float g = acc[m][q][j];
          float u = acc[m][q + 2][j];
          float sc = (colh < 4096) ? coef[row * 8 + (colh >> 9)] : 1.f;
          Hout[(size_t)row * 5120 + colh] = f2bf(g / (1.f + __expf(-g)) * u * sc);
        }
      }
  } else {
    float* dst = split ? Fout2 : Fout;
    const int rb = m0 + wr * 64 + lg * 4;
    const int cb = n0 + wc * 64;
#pragma unroll
    for (int m = 0; m < 4; ++m)
#pragma unroll
      for (int n = 0; n < 4; ++n)
#pragma unroll
        for (int j = 0; j < 4; ++j)
          dst[(size_t)(rb + m * 16 + j) * 1024 + cb + n * 16 + l15] = acc[m][n][j];
  }
}

// ---------------- split-K reduce: out += p1 ----------------
__global__ void reduce_add(float* __restrict__ out, const float* __restrict__ p1) {
  int i = blockIdx.x * 256 + threadIdx.x;
  float4 a = ((const float4*)out)[i];
  float4 b = ((const float4*)p1)[i];
  a.x += b.x; a.y += b.y; a.z += b.z; a.w += b.w;
  ((float4*)out)[i] = a;
}

extern "C" void kernel_launch(void* const* d_in, const int* in_sizes, int n_in,
                              void* d_out, int out_size, void* d_ws, size_t ws_size,
                              hipStream_t stream) {
  const float* x  = (const float*)d_in[0];
  const float* rw = (const float*)d_in[1];
  const float* eg = (const float*)d_in[2];
  const float* eu = (const float*)d_in[3];
  const float* ed = (const float*)d_in[4];
  const float* sg = (const float*)d_in[5];
  const float* su = (const float*)d_in[6];
  const float* sd = (const float*)d_in[7];
  float* out = (float*)d_out;

  char* ws = (char*)d_ws;
  u16*   Xb   = (u16*)(ws);                    // 8,388,608 B
  u16*   WpT  = (u16*)(ws + 8388608);          // 20,971,520 B
  u16*   WdT  = (u16*)(ws + 29360128);         // 10,485,760 B
  u16*   Hm   = (u16*)(ws + 39845888);         // 41,943,040 B
  float* coef = (float*)(ws + 81788928);       // 131,072 B
  float* p1   = (float*)(ws);                  // 16 MB split-K partial; overlays
                                               // Xb+WpT (dead after gu_gemm)

  mega<<<6912, 256, 0, stream>>>(x, rw, eg, eu, ed, sg, su, sd, Xb, WpT, WdT, coef);

  // gate/up: C[4096 x 10240] -> SwiGLU*coef -> Hm[4096 x 5120] bf16
  gemm8p<128, 256, 2, 4, true><<<1280, 512, 0, stream>>>(
      Xb, WpT, 1024, 1024, 32, coef, Hm, nullptr, nullptr);

  // down: out[4096 x 1024] = Hm[4096 x 5120] * WdT^T, split-K x2
  gemm8p<256, 128, 4, 2, false><<<256, 512, 0, stream>>>(
      Hm, WdT, 5120, 5120, 80, nullptr, nullptr, out, p1);

  reduce_add<<<4096, 256, 0, stream>>>(out, p1);
}

// Round 4
// 192.064 us; speedup vs baseline: 1.4754x; 1.0743x over previous
//
#include <hip/hip_runtime.h>
#include <hip/hip_bf16.h>
#include <stdint.h>

typedef short bf16x8 __attribute__((ext_vector_type(8)));
typedef float f32x4 __attribute__((ext_vector_type(4)));
typedef unsigned short u16;

#define GLOAD16(gp, lp)                                                        \
  __builtin_amdgcn_global_load_lds(                                            \
      (const __attribute__((address_space(1))) void*)(gp),                     \
      (__attribute__((address_space(3))) void*)(lp), 16, 0, 0)

__device__ __forceinline__ u16 f2bf(float f) {
  uint32_t u = __builtin_bit_cast(uint32_t, f);
  u = (u + 0x7FFFu + ((u >> 16) & 1u)) >> 16;
  return (u16)u;
}

// physical byte offset within an LDS region for logical (row, 16B-unit u∈0..3)
__device__ __forceinline__ int swzoff(int row, int u) {
  int p = row >> 1;
  int us = ((row & 1) * 4 + u) ^ (p & 7);
  return p * 128 + us * 16;
}

// ================= mega pre-pass: all packing + router in ONE launch ========
__global__ void mega(const float* __restrict__ x, const float* __restrict__ rw,
                     const float* __restrict__ eg, const float* __restrict__ eu,
                     const float* __restrict__ ed, const float* __restrict__ sg,
                     const float* __restrict__ su, const float* __restrict__ sd,
                     u16* __restrict__ Xb, u16* __restrict__ WpT,
                     u16* __restrict__ WdT, float* __restrict__ coef) {
  __shared__ float t[64][65];
  const int tid = threadIdx.x;
  const int b = blockIdx.x;
  if (b < 1280) {
    const float* src; int kbase, kt, ht;
    if (b < 1024) { src = ed; kbase = 0;    kt = b >> 4;          ht = b & 15; }
    else          { src = sd; kbase = 4096; kt = (b - 1024) >> 4; ht = b & 15; }
    const int k0 = kt * 64, h0 = ht * 64;
#pragma unroll
    for (int p = 0; p < 4; ++p) {
      int r = p * 16 + (tid >> 4), c = (tid & 15) * 4;
      float4 v = *(const float4*)&src[(size_t)(k0 + r) * 1024 + h0 + c];
      t[r][c] = v.x; t[r][c + 1] = v.y; t[r][c + 2] = v.z; t[r][c + 3] = v.w;
    }
    __syncthreads();
#pragma unroll
    for (int p = 0; p < 4; ++p) {
      int hl = p * 16 + (tid >> 4), kl = (tid & 15) * 4;
      ushort4 o;
      o.x = f2bf(t[kl][hl]);     o.y = f2bf(t[kl + 1][hl]);
      o.z = f2bf(t[kl + 2][hl]); o.w = f2bf(t[kl + 3][hl]);
      *(ushort4*)&WdT[(size_t)(h0 + hl) * 5120 + kbase + k0 + kl] = o;
    }
  } else if (b < 3840) {
    int bb = b - 1280;
    const float* src; int pbase, C, dt, ht;
    if (bb < 2048) {
      int slice = bb >> 7, r = bb & 127;
      int e = slice >> 1; int up = slice & 1;
      src = (up ? eu : eg) + (size_t)e * 524288;
      pbase = e * 1024 + up * 32; C = 512;
      dt = r >> 4; ht = r & 15;
    } else {
      int r = bb - 2048;
      int up = r >= 256; r &= 255;
      src = up ? su : sg; pbase = 8192 + up * 32; C = 1024;
      dt = r >> 4; ht = r & 15;
    }
    const int d0 = dt * 64, h0 = ht * 64;
#pragma unroll
    for (int p = 0; p < 4; ++p) {
      int hl = p * 16 + (tid >> 4), dl = (tid & 15) * 4;
      float4 v = *(const float4*)&src[(size_t)(h0 + hl) * C + d0 + dl];
      t[hl][dl] = v.x; t[hl][dl + 1] = v.y; t[hl][dl + 2] = v.z; t[hl][dl + 3] = v.w;
    }
    __syncthreads();
#pragma unroll
    for (int p = 0; p < 4; ++p) {
      int dl = p * 16 + (tid >> 4), hl = (tid & 15) * 4;
      int d = d0 + dl;
      int prow = pbase + ((d >> 5) << 6) + (d & 31);
      ushort4 o;
      o.x = f2bf(t[hl][dl]);     o.y = f2bf(t[hl + 1][dl]);
      o.z = f2bf(t[hl + 2][dl]); o.w = f2bf(t[hl + 3][dl]);
      *(ushort4*)&WpT[(size_t)prow * 1024 + h0 + hl] = o;
    }
  } else if (b < 4864) {
    const int l = tid & 63;
    const int tok = (b - 3840) * 4 + (tid >> 6);
    const float* xr = x + (size_t)tok * 1024;
    float acc[8];
#pragma unroll
    for (int e = 0; e < 8; ++e) acc[e] = 0.f;
    for (int it = 0; it < 16; ++it) {
      int h = it * 64 + l;
      float xv = xr[h];
      float4 r0 = *(const float4*)&rw[h * 8];
      float4 r1 = *(const float4*)&rw[h * 8 + 4];
      acc[0] += xv * r0.x; acc[1] += xv * r0.y; acc[2] += xv * r0.z; acc[3] += xv * r0.w;
      acc[4] += xv * r1.x; acc[5] += xv * r1.y; acc[6] += xv * r1.z; acc[7] += xv * r1.w;
    }
#pragma unroll
    for (int off = 32; off >= 1; off >>= 1) {
#pragma unroll
      for (int e = 0; e < 8; ++e) acc[e] += __shfl_xor(acc[e], off, 64);
    }
    if (l == 0) {
      float m = acc[0];
#pragma unroll
      for (int e = 1; e < 8; ++e) m = fmaxf(m, acc[e]);
      float p[8], s = 0.f;
#pragma unroll
      for (int e = 0; e < 8; ++e) { p[e] = expf(acc[e] - m); s += p[e]; }
      int i1 = 0;
#pragma unroll
      for (int e = 1; e < 8; ++e) if (p[e] > p[i1]) i1 = e;
      int i2 = (i1 == 0) ? 1 : 0;
#pragma unroll
      for (int e = 0; e < 8; ++e) if (e != i1 && p[e] > p[i2]) i2 = e;
      float inv = 1.f / s;
#pragma unroll
      for (int e = 0; e < 8; ++e) coef[tok * 8 + e] = (e == i1 || e == i2) ? p[e] * inv : 0.f;
    }
  } else {
    int i = (b - 4864) * 512 + tid;
#pragma unroll
    for (int k = 0; k < 2; ++k) {
      float4 v = ((const float4*)x)[i + k * 256];
      ushort4 o;
      o.x = f2bf(v.x); o.y = f2bf(v.y); o.z = f2bf(v.z); o.w = f2bf(v.w);
      ((ushort4*)Xb)[i + k * 256] = o;
    }
  }
}

// ============ counted-vmcnt pipelined GEMM (BK=32, 4-slot LDS ring) =========
// XCD-footprint-minimizing block mapping:
//   GU:   2 row-groups x 4 col-groups of XCDs; per-XCD A-slice 4MB (L2-resident),
//         B streams once -> total fetch ~74MB.
//   down: 4 row-groups x 2 col-groups, both K-splits co-located -> ~126MB.
template <int BM, int BN, int WM, int WN, bool GU>
__global__ __launch_bounds__(512, 2) void gemm8p(
    const u16* __restrict__ Ag, const u16* __restrict__ Bg,
    int lda, int ldb, int nt,
    const float* __restrict__ coef, u16* __restrict__ Hout,
    float* __restrict__ Fout, float* __restrict__ Fout2) {
  constexpr int SA = BM / 128;
  constexpr int SB = BN / 128;
  constexpr int BOFF = BM * 64;
  constexpr int SLOT = (BM + BN) * 64;
  __shared__ __align__(16) char lds[4 * SLOT];

  const int tid = threadIdx.x;
  const int l = tid & 63, l15 = l & 15, lg = l >> 4;
  const int wv = tid >> 6;
  const int wr = wv / WN, wc = wv % WN;

  int mT, nT, split = 0;
  if constexpr (GU) {
    // 1280 blocks; xcd = id&7; 2x4 groups; within: m-fastest (16m x 10n)
    int id = blockIdx.x;
    int xcd = id & 7, pos = id >> 3;
    int rG = xcd >> 2, cG = xcd & 3;
    int mL = pos & 15, nL = pos >> 4;
    mT = rG * 16 + mL; nT = cG * 10 + nL;
  } else {
    // 256 blocks; 4x2 groups; within: split-major, then 4m x 4n m-fastest
    int id = blockIdx.x;
    int xcd = id & 7, pos = id >> 3;
    int mG = xcd >> 1, cG = xcd & 1;
    split = pos >> 4; int r = pos & 15;
    int mL = r & 3, nL = r >> 2;
    mT = mG * 4 + mL; nT = cG * 4 + nL;
  }
  const int m0 = mT * BM, n0 = nT * BN;
  const int kbase = GU ? 0 : split * 2560;

  const char* gA[SA]; int lA[SA];
  const char* gB[SB]; int lB[SB];
#pragma unroll
  for (int j = 0; j < SA; ++j) {
    int L = (j * 512 + tid) * 16;
    int p = L >> 7, uph = (L >> 4) & 7;
    int usw = uph ^ (p & 7);
    int row = 2 * p + (usw >> 2), ulog = usw & 3;
    gA[j] = (const char*)(Ag + (size_t)(m0 + row) * lda + kbase) + ulog * 16;
    lA[j] = L;
  }
#pragma unroll
  for (int j = 0; j < SB; ++j) {
    int L = (j * 512 + tid) * 16;
    int p = L >> 7, uph = (L >> 4) & 7;
    int usw = uph ^ (p & 7);
    int row = 2 * p + (usw >> 2), ulog = usw & 3;
    gB[j] = (const char*)(Bg + (size_t)(n0 + row) * ldb + kbase) + ulog * 16;
    lB[j] = L;
  }

  int offA[4], offB[4];
#pragma unroll
  for (int m = 0; m < 4; ++m) offA[m] = swzoff(wr * 64 + m * 16 + l15, lg);
#pragma unroll
  for (int n = 0; n < 4; ++n) offB[n] = BOFF + swzoff(wc * 64 + n * 16 + l15, lg);

  f32x4 acc[4][4];
#pragma unroll
  for (int m = 0; m < 4; ++m)
#pragma unroll
    for (int n = 0; n < 4; ++n) acc[m][n] = {0.f, 0.f, 0.f, 0.f};

#define STAGE(T)                                                               \
  {                                                                            \
    char* sb_ = lds + (((T) & 3) * SLOT);                                      \
    const int tb_ = (T) * 64;                                                  \
    _Pragma("unroll") for (int j = 0; j < SA; ++j)                             \
        GLOAD16(gA[j] + tb_, sb_ + lA[j]);                                     \
    _Pragma("unroll") for (int j = 0; j < SB; ++j)                             \
        GLOAD16(gB[j] + tb_, sb_ + BOFF + lB[j]);                              \
  }

  STAGE(0); STAGE(1); STAGE(2);
  asm volatile("s_waitcnt vmcnt(6)" ::: "memory");
  __builtin_amdgcn_s_barrier();

  for (int t = 0; t < nt; ++t) {
    asm volatile("" ::: "memory");
    char* sb = lds + ((t & 3) * SLOT);
    bf16x8 af[4], bfr[4];
#pragma unroll
    for (int m = 0; m < 4; ++m) af[m] = *(const bf16x8*)(sb + offA[m]);
#pragma unroll
    for (int n = 0; n < 4; ++n) bfr[n] = *(const bf16x8*)(sb + offB[n]);
    if (t + 3 < nt) STAGE(t + 3);
    asm volatile("s_waitcnt vmcnt(6)" ::: "memory");
    __builtin_amdgcn_s_barrier();
    __builtin_amdgcn_s_setprio(1);
#pragma unroll
    for (int m = 0; m < 4; ++m)
#pragma unroll
      for (int n = 0; n < 4; ++n)
        acc[m][n] = __builtin_amdgcn_mfma_f32_16x16x32_bf16(af[m], bfr[n], acc[m][n], 0, 0, 0);
    __builtin_amdgcn_s_setprio(0);
    asm volatile("" ::: "memory");
    __builtin_amdgcn_s_barrier();
  }
#undef STAGE

  if constexpr (GU) {
    const int rb = m0 + wr * 64 + lg * 4;
    const int hb = (n0 + wc * 64) >> 1;
#pragma unroll
    for (int m = 0; m < 4; ++m)
#pragma unroll
      for (int q = 0; q < 2; ++q) {
        int colh = hb + q * 16 + l15;
#pragma unroll
        for (int j = 0; j < 4; ++j) {
          int row = rb + m * 16 + j;
          float g = acc[m][q][j];
          float u = acc[m][q + 2][j];
          float sc = (colh < 4096) ? coef[row * 8 + (colh >> 9)] : 1.f;
          Hout[(size_t)row * 5120 + colh] = f2bf(g / (1.f + __expf(-g)) * u * sc);
        }
      }
  } else {
    float* dst = split ? Fout2 : Fout;
    const int rb = m0 + wr * 64 + lg * 4;
    const int cb = n0 + wc * 64;
#pragma unroll
    for (int m = 0; m < 4; ++m)
#pragma unroll
      for (int n = 0; n < 4; ++n)
#pragma unroll
        for (int j = 0; j < 4; ++j)
          dst[(size_t)(rb + m * 16 + j) * 1024 + cb + n * 16 + l15] = acc[m][n][j];
  }
}

// ---------------- split-K reduce: out += p1 ----------------
__global__ void reduce_add(float* __restrict__ out, const float* __restrict__ p1) {
  int i = blockIdx.x * 256 + threadIdx.x;
  float4 a = ((const float4*)out)[i];
  float4 b = ((const float4*)p1)[i];
  a.x += b.x; a.y += b.y; a.z += b.z; a.w += b.w;
  ((float4*)out)[i] = a;
}

extern "C" void kernel_launch(void* const* d_in, const int* in_sizes, int n_in,
                              void* d_out, int out_size, void* d_ws, size_t ws_size,
                              hipStream_t stream) {
  const float* x  = (const float*)d_in[0];
  const float* rw = (const float*)d_in[1];
  const float* eg = (const float*)d_in[2];
  const float* eu = (const float*)d_in[3];
  const float* ed = (const float*)d_in[4];
  const float* sg = (const float*)d_in[5];
  const float* su = (const float*)d_in[6];
  const float* sd = (const float*)d_in[7];
  float* out = (float*)d_out;

  char* ws = (char*)d_ws;
  u16*   Xb   = (u16*)(ws);                    // 8,388,608 B
  u16*   WpT  = (u16*)(ws + 8388608);          // 20,971,520 B
  u16*   WdT  = (u16*)(ws + 29360128);         // 10,485,760 B
  u16*   Hm   = (u16*)(ws + 39845888);         // 41,943,040 B
  float* coef = (float*)(ws + 81788928);       // 131,072 B
  float* p1   = (float*)(ws);                  // 16 MB split-K partial (overlays Xb/WpT)

  mega<<<6912, 256, 0, stream>>>(x, rw, eg, eu, ed, sg, su, sd, Xb, WpT, WdT, coef);

  gemm8p<128, 256, 2, 4, true><<<1280, 512, 0, stream>>>(
      Xb, WpT, 1024, 1024, 32, coef, Hm, nullptr, nullptr);

  gemm8p<256, 128, 4, 2, false><<<256, 512, 0, stream>>>(
      Hm, WdT, 5120, 5120, 80, nullptr, nullptr, out, p1);

  reduce_add<<<4096, 256, 0, stream>>>(out, p1);
}